// Round 18
// baseline (625.330 us; speedup 1.0000x reference)
//
#include <hip/hip_runtime.h>
#include <hip/hip_bf16.h>

#define BB 16
#define NN 1024
#define KNN 20

typedef __attribute__((ext_vector_type(8))) short bf16x8;   // 8 bf16 (4 VGPRs)
typedef __attribute__((ext_vector_type(4))) float f32x4;

__device__ __forceinline__ unsigned short f2b(float f){
    __hip_bfloat16 h = __float2bfloat16(f);
    return *(unsigned short*)&h;
}

// ---------------- fallback: encode ws_size into output if workspace too small ----------------
__global__ void fallback_k(float* __restrict__ out, int n, float c){
    int i = blockIdx.x*256 + threadIdx.x;
    if(i < n) out[i] = c;
}

// ---------------- transpose x [16,1024,3] -> hT [16][3][1024] + sqnorm (same fma chain) --------
__global__ void transpose3s_k(const float* __restrict__ x, float* __restrict__ hT,
                              float* __restrict__ sqn){
    int i = blockIdx.x*256 + threadIdx.x;
    if(i < BB*NN){
        int b = i >> 10, n = i & 1023;
        float s = 0.f;
        #pragma unroll
        for(int d=0; d<3; d++){
            float v = x[(size_t)i*3 + d];
            hT[((size_t)b*3 + d)*NN + n] = v;
            s = fmaf(v, v, s);
        }
        sqn[i] = s;
    }
}

// ---------------- transpose hs slice -> hT [16][D][1024] + sqnorm (ascending-d chain) ----------
template<int D>
__global__ __launch_bounds__(256) void transq_k(const float* __restrict__ src,
                                                float* __restrict__ hT,
                                                float* __restrict__ sqn){
    int nt = blockIdx.x, b = blockIdx.y;
    int tid = threadIdx.x;
    __shared__ float tile[64][65];
    int n0 = nt*64;
    float s = 0.f;
    for(int ct=0; ct<D/64; ct++){
        int c0 = ct*64;
        if(ct) __syncthreads();
        for(int l=tid; l<64*64; l+=256){
            int r = l>>6, c = l&63;
            tile[r][c] = src[(size_t)(b*NN + n0 + r)*512 + c0 + c];
        }
        __syncthreads();
        for(int l=tid; l<64*64; l+=256){
            int d = l>>6, n = l&63;
            hT[((size_t)b*D + c0 + d)*NN + n0 + n] = tile[n][d];
        }
        if(tid < 64){
            for(int c=0;c<64;c++){ float v = tile[tid][c]; s = fmaf(v, v, s); }
        }
    }
    if(tid < 64) sqn[b*NN + n0 + tid] = s;
}

// ---------------- FUSED: knn (dist-GEMM + u32-tournament top-20) || featTU fp32 GEMM -----------
// knn path: verbatim round 17 (bit-identical indices).
// feat path (r18): [k][row] LDS layout, float4 fragments -> 3 ds_read_b128 + 32 fma per k
// (was 12 ds_read_b32 + 32 fma). Per-output fma chain order unchanged -> bit-identical T/U.
template<int D, int O>
__global__ __launch_bounds__(256, 4) void knnfeat_k(const float* __restrict__ hT,
                                                    const float* __restrict__ sqn,
                                                    int* __restrict__ idx,
                                                    const float* __restrict__ h, int S,
                                                    const float* __restrict__ th,
                                                    const float* __restrict__ ph,
                                                    float* __restrict__ T,
                                                    float* __restrict__ hsU){
    constexpr int F = (O/64)*256;     // feat blocks
    constexpr int R = 2048/F;         // knn blocks per feat block
    constexpr int G = R + 1;
    constexpr int SM_KNN  = 32768 + D*32 + 32;
    constexpr int SM_FEAT = 3*32*68*4;            // 26112: As,Wt,Wp [32][68] floats
    constexpr int SM = SM_KNN > SM_FEAT ? SM_KNN : SM_FEAT;
    __shared__ __align__(16) char smem[SM];
    const int tid = threadIdx.x;

    const int bq = blockIdx.x / G;
    const int br = blockIdx.x % G;

    if(br != R){
        // ================= knn path =================
        const int kid  = bq*R + br;
        const int b    = kid >> 7;
        const int n0   = (kid & 127) * 8;
        const int lane = tid & 63;
        const int wv   = tid >> 6;

        float4* distb4 = (float4*)smem;
        float*  rowsA  = (float*)(smem + 32768);
        float*  sqnA   = (float*)(smem + 32768 + D*32);

        const float* hTb = hT + (size_t)b*D*NN;
        for(int l=tid; l<8*D; l+=256){
            int d = l >> 3, r = l & 7;
            rowsA[l] = hTb[(size_t)d*NN + n0 + r];
        }
        if(tid < 8) sqnA[tid] = sqn[b*NN + n0 + tid];
        __syncthreads();

        const int c4 = wv*64 + lane;
        const float4* B4 = (const float4*)hTb;
        float4 acc[8];
        #pragma unroll
        for(int r=0;r<8;r++) acc[r] = make_float4(0.f,0.f,0.f,0.f);

        #pragma unroll 4
        for(int d=0; d<D; d++){
            float4 bv = B4[d*256 + c4];
            float4 a0 = *(const float4*)&rowsA[d*8];
            float4 a1 = *(const float4*)&rowsA[d*8 + 4];
            float ar[8] = {a0.x,a0.y,a0.z,a0.w,a1.x,a1.y,a1.z,a1.w};
            #pragma unroll
            for(int r=0;r<8;r++){
                acc[r].x = fmaf(ar[r], bv.x, acc[r].x);
                acc[r].y = fmaf(ar[r], bv.y, acc[r].y);
                acc[r].z = fmaf(ar[r], bv.z, acc[r].z);
                acc[r].w = fmaf(ar[r], bv.w, acc[r].w);
            }
        }

        float4 sq4 = ((const float4*)(sqn + b*NN))[c4];
        #pragma unroll
        for(int r=0;r<8;r++){
            float sa = sqnA[r];
            float4 dv;
            dv.x = sa + sq4.x - 2.f*acc[r].x;
            dv.y = sa + sq4.y - 2.f*acc[r].y;
            dv.z = sa + sq4.z - 2.f*acc[r].z;
            dv.w = sa + sq4.w - 2.f*acc[r].w;
            distb4[r*256 + c4] = dv;
        }
        __syncthreads();

        // ---- top-20 for rows 2wv, 2wv+1: tournaments interleaved (ILP-2) ----
        const int r0 = 2*wv, r1 = 2*wv + 1;
        unsigned s0[16], s1[16];
        {
            const float4* p0 = &distb4[r0*256];
            const float4* p1 = &distb4[r1*256];
            #pragma unroll
            for(int q4=0;q4<4;q4++){
                float4 f0 = p0[lane + 64*q4];
                float4 f1 = p1[lane + 64*q4];
                float v0[4]={f0.x,f0.y,f0.z,f0.w}, v1[4]={f1.x,f1.y,f1.z,f1.w};
                #pragma unroll
                for(int c=0;c<4;c++){
                    unsigned u0=__float_as_uint(v0[c]); u0 ^= (unsigned)((int)u0>>31)|0x80000000u;
                    unsigned u1=__float_as_uint(v1[c]); u1 ^= (unsigned)((int)u1>>31)|0x80000000u;
                    s0[q4*4+c]=(u0&0xFFFFFFF0u)|(unsigned)(q4*4+c);
                    s1[q4*4+c]=(u1&0xFFFFFFF0u)|(unsigned)(q4*4+c);
                }
            }
        }
        // bitonic sort ascending, both rows interleaved (registers only)
        #pragma unroll
        for(int k=2;k<=16;k<<=1){
            #pragma unroll
            for(int j=k>>1;j>0;j>>=1){
                #pragma unroll
                for(int i=0;i<16;i++){
                    int l = i ^ j;
                    if(l > i){
                        bool up = ((i & k) == 0);
                        unsigned a, b2, lo, hi;
                        a=s0[i]; b2=s0[l]; lo=a<b2?a:b2; hi=a<b2?b2:a; s0[i]=up?lo:hi; s0[l]=up?hi:lo;
                        a=s1[i]; b2=s1[l]; lo=a<b2?a:b2; hi=a<b2?b2:a; s1[i]=up?lo:hi; s1[l]=up?hi:lo;
                    }
                }
            }
        }
        // q-major dump into the dead dist rows (conflict-free)
        unsigned* sb0 = (unsigned*)distb4 + r0*1024;
        unsigned* sb1 = (unsigned*)distb4 + r1*1024;
        #pragma unroll
        for(int q=0;q<16;q++){ sb0[q*64 + lane] = s0[q]; sb1[q*64 + lane] = s1[q]; }

        int cnt0 = 0, cnt1 = 0;
        unsigned cur0 = (s0[0] & 0xFFFFFFC0u) | (unsigned)lane;
        unsigned cur1 = (s1[0] & 0xFFFFFFC0u) | (unsigned)lane;
        int q00 = s0[0] & 15, q10 = s1[0] & 15;
        int g0v = 4*lane + 256*(q00>>2) + (q00&3);
        int g1v = 4*lane + 256*(q10>>2) + (q10&3);
        int* out0 = idx + ((size_t)b*NN + n0 + r0)*KNN;
        int* out1 = idx + ((size_t)b*NN + n0 + r1)*KNN;
        for(int t=0;t<KNN;t++){
            unsigned w0 = cur0, w1 = cur1;
            #pragma unroll
            for(int off=32; off>0; off>>=1){
                unsigned o0 = __shfl_xor(w0, off);
                unsigned o1 = __shfl_xor(w1, off);
                w0 = w0 < o0 ? w0 : o0;
                w1 = w1 < o1 ? w1 : o1;
            }
            int g0 = __shfl(g0v, (int)(w0 & 63));
            int g1 = __shfl(g1v, (int)(w1 & 63));
            if(lane == 0){ out0[t] = g0; out1[t] = g1; }
            if(w0 == cur0){
                cnt0++;
                unsigned hn = sb0[(cnt0 & 15)*64 + lane];
                if(cnt0 >= 16) hn = 0xFFFFFFFFu;
                int q = hn & 15; g0v = 4*lane + 256*(q>>2) + (q&3);
                cur0 = (hn & 0xFFFFFFC0u) | (unsigned)lane;
            }
            if(w1 == cur1){
                cnt1++;
                unsigned hn = sb1[(cnt1 & 15)*64 + lane];
                if(cnt1 >= 16) hn = 0xFFFFFFFFu;
                int q = hn & 15; g1v = 4*lane + 256*(q>>2) + (q&3);
                cur1 = (hn & 0xFFFFFFC0u) | (unsigned)lane;
            }
        }
    } else {
        // ================= featTU path (fp32, vectorized [k][row] LDS fragments) ============
        int fid = bq;
        int ot = fid % (O/64);
        int nt = fid / (O/64);
        int tx = tid & 15, ty = tid >> 4;      // rows ty*4..+3, cols tx*4..+3
        float (*As)[68] = (float(*)[68])(smem);           // [k][row], stride 68 fl = 272 B
        float (*Wt)[68] = (float(*)[68])(smem + 8704);
        float (*Wp)[68] = (float(*)[68])(smem + 17408);
        float acct[4][4] = {};
        float accp[4][4] = {};
        for(int kk=0; kk<D; kk+=32){
            if(kk) __syncthreads();
            #pragma unroll
            for(int q=0; q<2; q++){
                int idx2 = tid + 256*q;        // 0..511
                int r  = idx2 >> 3;            // 0..63
                int c0 = (idx2 & 7)*4;         // k-local 0..28
                float4 av, tv, pv;
                if constexpr (D % 32 == 0){
                    av = *(const float4*)&h[(size_t)(nt*64+r)*S + kk + c0];
                    tv = *(const float4*)&th[(size_t)(ot*64+r)*D + kk + c0];
                    pv = *(const float4*)&ph[(size_t)(ot*64+r)*D + kk + c0];
                } else {
                    float a4[4], t4[4], p4[4];
                    #pragma unroll
                    for(int i=0;i<4;i++){
                        int d = kk + c0 + i;
                        a4[i] = (d < D) ? h[(size_t)(nt*64+r)*S + d] : 0.f;
                        t4[i] = (d < D) ? th[(size_t)(ot*64+r)*D + d] : 0.f;
                        p4[i] = (d < D) ? ph[(size_t)(ot*64+r)*D + d] : 0.f;
                    }
                    av = make_float4(a4[0],a4[1],a4[2],a4[3]);
                    tv = make_float4(t4[0],t4[1],t4[2],t4[3]);
                    pv = make_float4(p4[0],p4[1],p4[2],p4[3]);
                }
                As[c0+0][r]=av.x; As[c0+1][r]=av.y; As[c0+2][r]=av.z; As[c0+3][r]=av.w;
                Wt[c0+0][r]=tv.x; Wt[c0+1][r]=tv.y; Wt[c0+2][r]=tv.z; Wt[c0+3][r]=tv.w;
                Wp[c0+0][r]=pv.x; Wp[c0+1][r]=pv.y; Wp[c0+2][r]=pv.z; Wp[c0+3][r]=pv.w;
            }
            __syncthreads();
            #pragma unroll
            for(int k=0;k<32;k++){
                float4 a4  = *(const float4*)&As[k][ty*4];
                float4 bt4 = *(const float4*)&Wt[k][tx*4];
                float4 bp4 = *(const float4*)&Wp[k][tx*4];
                float a[4]  = {a4.x, a4.y, a4.z, a4.w};
                float bt[4] = {bt4.x, bt4.y, bt4.z, bt4.w};
                float bp[4] = {bp4.x, bp4.y, bp4.z, bp4.w};
                #pragma unroll
                for(int i=0;i<4;i++)
                    #pragma unroll
                    for(int j=0;j<4;j++){
                        acct[i][j] = fmaf(a[i], bt[j], acct[i][j]);
                        accp[i][j] = fmaf(a[i], bp[j], accp[i][j]);
                    }
            }
        }
        #pragma unroll
        for(int i=0;i<4;i++){
            int rw = nt*64 + ty*4 + i;
            int oc = ot*64 + tx*4;
            *(float4*)&T[(size_t)rw*O + oc] =
                make_float4(acct[i][0], acct[i][1], acct[i][2], acct[i][3]);
            *(float4*)&hsU[(size_t)rw*512 + oc] =
                make_float4(accp[i][0]-acct[i][0], accp[i][1]-acct[i][1],
                            accp[i][2]-acct[i][2], accp[i][3]-acct[i][3]);
        }
    }
}

// ---------------- gather 20 neighbors of T, max, + U (in-place in hs slice), leaky -------------
template<int O>
__global__ __launch_bounds__(256) void gather2_k(const float* __restrict__ T,
                                                 const int* __restrict__ idx,
                                                 float* __restrict__ outp){
    constexpr int P = 256 / O;           // points per block
    int bn0 = blockIdx.x * P;
    int tid = threadIdx.x;
    int p = tid / O, o = tid % O;
    int bn = bn0 + p;
    int b  = bn >> 10;
    __shared__ int nb[P*KNN];
    if(tid < P*KNN){
        int pp = tid / KNN, k = tid % KNN;
        nb[pp*KNN + k] = idx[(size_t)(bn0+pp)*KNN + k] & (NN-1);  // mask: never faults
    }
    __syncthreads();
    const float* Tb = T + (size_t)b*NN*O;
    float m = -3.402823466e38f;
    #pragma unroll
    for(int k=0;k<KNN;k++) m = fmaxf(m, Tb[(size_t)nb[p*KNN+k]*O + o]);
    float v = m + outp[(size_t)bn*512 + o];      // U was staged here by knnfeat
    v = (v > 0.f) ? v : 0.2f*v;
    outp[(size_t)bn*512 + o] = v;
}

// ---------------- merged casts: hs [16384,512] f32->bf16 and proj_w [1024,512] f32->bf16 -------
__global__ __launch_bounds__(256) void castall_k(const float* __restrict__ hs, unsigned short* __restrict__ hb,
                                                 const float* __restrict__ w, unsigned short* __restrict__ wb){
    const float4* in4;
    unsigned short* dst;
    int i;
    if(blockIdx.x < 4096){ i = blockIdx.x*256 + threadIdx.x; in4 = (const float4*)hs; dst = hb; }
    else                 { i = (blockIdx.x-4096)*256 + threadIdx.x; in4 = (const float4*)w;  dst = wb; }
    float4 a = in4[2*i], c = in4[2*i+1];
    unsigned short t[8];
    t[0]=f2b(a.x); t[1]=f2b(a.y); t[2]=f2b(a.z); t[3]=f2b(a.w);
    t[4]=f2b(c.x); t[5]=f2b(c.y); t[6]=f2b(c.z); t[7]=f2b(c.w);
    *(ulonglong2*)&dst[8*i] = *(ulonglong2*)t;
}

// ---------------- projection GEMM via bf16 MFMA: 128x128 tile, max-pool epilogue ----------------
__global__ __launch_bounds__(256) void proj3_k(const unsigned short* __restrict__ hsb,
                                               const unsigned short* __restrict__ wb,
                                               float* __restrict__ pmax){
    int bi = blockIdx.x;
    int ot = bi >> 7;             // col tile (0..7) in high bits -> A-tile sharers on same XCD
    int nb = bi & 127;
    int b  = nb >> 3, nt = nb & 7;
    int tid = threadIdx.x, lane = tid & 63, wv = tid >> 6;
    int quad = lane >> 4, m = lane & 15;

    __shared__ __align__(16) unsigned short Ab[128*40];   // row stride 40 bf16 = 80 B
    __shared__ __align__(16) unsigned short Bb[128*40];

    f32x4 acc[8][2] = {};
    const unsigned short* ha = hsb + ((size_t)(b*NN + nt*128))*512;
    const unsigned short* wa = wb + (size_t)ot*128*512;

    for(int kk=0; kk<512; kk+=32){
        __syncthreads();
        #pragma unroll
        for(int q=0; q<2; q++){
            int idx = tid + 256*q;
            int r = idx >> 2, sg = idx & 3;
            ulonglong2 va = *(const ulonglong2*)&ha[(size_t)r*512 + kk + sg*8];
            ulonglong2 vw = *(const ulonglong2*)&wa[(size_t)r*512 + kk + sg*8];
            *(ulonglong2*)&Ab[r*40 + sg*8] = va;
            *(ulonglong2*)&Bb[r*40 + sg*8] = vw;
        }
        __syncthreads();
        bf16x8 bf0 = *(bf16x8*)&Bb[(wv*32 + m)*40 + quad*8];
        bf16x8 bf1 = *(bf16x8*)&Bb[(wv*32 + 16 + m)*40 + quad*8];
        #pragma unroll
        for(int rt=0; rt<8; rt++){
            bf16x8 af = *(bf16x8*)&Ab[(rt*16 + m)*40 + quad*8];
            acc[rt][0] = __builtin_amdgcn_mfma_f32_16x16x32_bf16(af, bf0, acc[rt][0], 0,0,0);
            acc[rt][1] = __builtin_amdgcn_mfma_f32_16x16x32_bf16(af, bf1, acc[rt][1], 0,0,0);
        }
    }

    #pragma unroll
    for(int ct=0; ct<2; ct++){
        float mx = acc[0][ct][0];
        #pragma unroll
        for(int rt=0; rt<8; rt++)
            #pragma unroll
            for(int r=0; r<4; r++) mx = fmaxf(mx, acc[rt][ct][r]);
        mx = fmaxf(mx, __shfl_xor(mx, 16));
        mx = fmaxf(mx, __shfl_xor(mx, 32));
        if(quad == 0)
            pmax[((size_t)b*8 + nt)*1024 + ot*128 + wv*32 + ct*16 + m] = mx;
    }
}

// ---------------- column sums of hs: colsum[16][512] (for algebraic mean-pool, fp32) ----------------
__global__ void colsum_k(const float* __restrict__ hs, float* __restrict__ colsum){
    int i = blockIdx.x*256 + threadIdx.x;   // b*512 + c
    if(i >= BB*512) return;
    int b = i >> 9, c = i & 511;
    const float* p = hs + (size_t)b*NN*512 + c;
    float s = 0.f;
    for(int n=0;n<NN;n++) s += p[(size_t)n*512];
    colsum[i] = s;
}

// ---------------- combine: max over 8 tiles; mean = colsum@w/1024 (fp32); + bias ----------------
__global__ __launch_bounds__(256) void pool_final2_k(const float* __restrict__ pmax,
                                                     const float* __restrict__ colsum,
                                                     const float* __restrict__ w,
                                                     const float* __restrict__ pb,
                                                     float* __restrict__ pooled){
    int i = blockIdx.x*256 + threadIdx.x;   // b*1024 + o
    int b = i >> 10, o = i & 1023;
    __shared__ float cs[512];
    for(int l=threadIdx.x; l<512; l+=256) cs[l] = colsum[b*512 + l];
    __syncthreads();
    float m = -3.402823466e38f;
    #pragma unroll
    for(int t=0;t<8;t++) m = fmaxf(m, pmax[((size_t)b*8 + t)*1024 + o]);
    float s = 0.f;
    const float4* w4 = (const float4*)(w + (size_t)o*512);
    const float4* c4 = (const float4*)cs;
    for(int d=0; d<128; d++){
        float4 wv = w4[d]; float4 cv = c4[d];
        s = fmaf(cv.x, wv.x, s); s = fmaf(cv.y, wv.y, s);
        s = fmaf(cv.z, wv.z, s); s = fmaf(cv.w, wv.w, s);
    }
    float bias = pb[o];
    pooled[b*2048 + o]        = m + bias;
    pooled[b*2048 + 1024 + o] = s * (1.f/1024.f) + bias;
}

// ---------------- head FC + BatchNorm(batch of 16) + leaky; one block per feature ----------------
template<int IN>
__global__ __launch_bounds__(256) void head_bn_k(const float* __restrict__ in, const float* __restrict__ w,
                                                 const float* __restrict__ bias, const float* __restrict__ g,
                                                 const float* __restrict__ bt, float* __restrict__ out, int OUT){
    int o = blockIdx.x;
    int tid = threadIdx.x, bb = tid >> 4, s = tid & 15;
    const float* ir = in + (size_t)bb*IN;
    const float* wr = w  + (size_t)o*IN;
    float acc = 0.f;
    for(int d=s; d<IN; d+=16) acc = fmaf(ir[d], wr[d], acc);
    #pragma unroll
    for(int off=8; off>0; off>>=1) acc += __shfl_xor(acc, off);
    __shared__ float vals[16];
    __shared__ float stats[2];
    if(s == 0) vals[bb] = acc + bias[o];
    __syncthreads();
    if(tid == 0){
        float mu = 0.f;
        for(int q=0;q<16;q++) mu += vals[q];
        mu *= (1.f/16.f);
        float var = 0.f;
        for(int q=0;q<16;q++){ float d = vals[q]-mu; var = fmaf(d,d,var); }
        var *= (1.f/16.f);
        stats[0] = mu; stats[1] = rsqrtf(var + 1e-5f);
    }
    __syncthreads();
    if(s == 0){
        float v = (vals[bb]-stats[0])*stats[1]*g[o] + bt[o];
        v = (v > 0.f) ? v : 0.2f*v;
        out[(size_t)bb*OUT + o] = v;
    }
}

// ---------------- final linear -> f32 out [16,40] ----------------
__global__ __launch_bounds__(256) void head_out_k(const float* __restrict__ in, const float* __restrict__ w,
                                                  const float* __restrict__ bias, float* __restrict__ out){
    int o = blockIdx.x;   // 40
    int tid = threadIdx.x, bb = tid >> 4, s = tid & 15;
    const float* ir = in + (size_t)bb*256;
    float acc = 0.f;
    for(int d=s; d<256; d+=16) acc = fmaf(ir[d], w[o*256+d], acc);
    #pragma unroll
    for(int off=8; off>0; off>>=1) acc += __shfl_xor(acc, off);
    if(s == 0) out[bb*40 + o] = acc + bias[o];
}

extern "C" void kernel_launch(void* const* d_in, const int* in_sizes, int n_in,
                              void* d_out, int out_size, void* d_ws, size_t ws_size,
                              hipStream_t stream) {
    const float* x       = (const float*)d_in[0];
    const float* th[4]   = {(const float*)d_in[1], (const float*)d_in[3], (const float*)d_in[5], (const float*)d_in[7]};
    const float* ph[4]   = {(const float*)d_in[2], (const float*)d_in[4], (const float*)d_in[6], (const float*)d_in[8]};
    const float* proj_w  = (const float*)d_in[9];
    const float* proj_b  = (const float*)d_in[10];
    const float* emb0_w  = (const float*)d_in[11];
    const float* emb0_b  = (const float*)d_in[12];
    const float* bn0_g   = (const float*)d_in[13];
    const float* bn0_b   = (const float*)d_in[14];
    const float* emb1_w  = (const float*)d_in[15];
    const float* emb1_b  = (const float*)d_in[16];
    const float* bn1_g   = (const float*)d_in[17];
    const float* bn1_b   = (const float*)d_in[18];
    const float* out_w   = (const float*)d_in[19];
    const float* out_b   = (const float*)d_in[20];
    float* outp = (float*)d_out;

    // workspace layout (float elements) — REQ unchanged (guard passed at 68.5 MB)
    const size_t OFF_HS  = 0;                       // 16384 x 512 = 8,388,608
    const size_t OFF_T   = 8388608;                 // T outputs (4,194,304)
    const size_t OFF_U   = 12582912;                // hT (<=2,097,152) then hsbf
    const size_t OFF_SQN = 16777216;                // 16384
    const size_t OFF_IDX = 16793600;                // 16384 x 20 ints = 327,680
    const size_t REQ_FL  = 17121280;
    const size_t REQ     = REQ_FL * 4;              // 68,485,120 bytes

    if(ws_size < REQ){
        fallback_k<<<(out_size+255)/256, 256, 0, stream>>>(outp, out_size, (float)((double)ws_size*1e-6));
        return;
    }

    float* Wf   = (float*)d_ws;
    float* hs   = Wf + OFF_HS;
    float* T    = Wf + OFF_T;
    float* hT   = Wf + OFF_U;                       // hT in old U region (no T alias)
    float* sqn  = Wf + OFF_SQN;
    int*   idxb = (int*)(Wf + OFF_IDX);
    // post-layer aliases (T region dead after last gather):
    float* pmax   = T;                                  // 131,072 fl
    float* colsum = T + 131072;
    float* pooled = T + 147456;
    float* z0     = T + 180224;
    float* z1     = T + 188416;
    unsigned short* wbf  = (unsigned short*)(T + 200704);   // 524,288 bf16 (inside T region)
    unsigned short* hsbf = (unsigned short*)(Wf + OFF_U);   // old U region (hT dead after layer 3)

    // ---- layer 0: h=x (S=3,D=3) -> O=64 at hs ch 0     (grid = 2048 knn + 256 feat, interleaved)
    transpose3s_k<<<64,256,0,stream>>>(x, hT, sqn);
    knnfeat_k<3,64><<<2304,256,0,stream>>>(hT, sqn, idxb, x, 3, th[0], ph[0], T, hs + 0);
    gather2_k<64><<<BB*NN/4,256,0,stream>>>(T, idxb, hs + 0);

    // ---- layer 1: h=hs[:,0:64] (S=512,D=64) -> O=64 at ch 64
    transq_k<64><<<dim3(16,16),256,0,stream>>>(hs + 0, hT, sqn);
    knnfeat_k<64,64><<<2304,256,0,stream>>>(hT, sqn, idxb, hs + 0, 512, th[1], ph[1], T, hs + 64);
    gather2_k<64><<<BB*NN/4,256,0,stream>>>(T, idxb, hs + 64);

    // ---- layer 2: h=hs[:,64:128] (D=64) -> O=128 at ch 128   (2048 + 512)
    transq_k<64><<<dim3(16,16),256,0,stream>>>(hs + 64, hT, sqn);
    knnfeat_k<64,128><<<2560,256,0,stream>>>(hT, sqn, idxb, hs + 64, 512, th[2], ph[2], T, hs + 128);
    gather2_k<128><<<BB*NN/2,256,0,stream>>>(T, idxb, hs + 128);

    // ---- layer 3: h=hs[:,128:256] (D=128) -> O=256 at ch 256  (2048 + 1024)
    transq_k<128><<<dim3(16,16),256,0,stream>>>(hs + 128, hT, sqn);
    knnfeat_k<128,256><<<3072,256,0,stream>>>(hT, sqn, idxb, hs + 128, 512, th[3], ph[3], T, hs + 256);
    gather2_k<256><<<BB*NN,256,0,stream>>>(T, idxb, hs + 256);

    // ---- casts (hT dead; hsbf reuses that region; wbf corner of T region)
    castall_k<<<4096+256,256,0,stream>>>(hs, hsbf, proj_w, wbf);

    // ---- projection + pooling (max via bf16 MFMA GEMM; mean via fp32 colsum @ w)
    proj3_k<<<1024,256,0,stream>>>(hsbf, wbf, pmax);
    colsum_k<<<32,256,0,stream>>>(hs, colsum);
    pool_final2_k<<<64,256,0,stream>>>(pmax, colsum, proj_w, proj_b, pooled);

    // ---- head
    head_bn_k<2048><<<512,256,0,stream>>>(pooled, emb0_w, emb0_b, bn0_g, bn0_b, z0, 512);
    head_bn_k<512><<<256,256,0,stream>>>(z0, emb1_w, emb1_b, bn1_g, bn1_b, z1, 256);
    head_out_k<<<40,256,0,stream>>>(z1, out_w, out_b, outp);
}

// Round 19
// 608.279 us; speedup vs baseline: 1.0280x; 1.0280x over previous
//
#include <hip/hip_runtime.h>
#include <hip/hip_bf16.h>

#define BB 16
#define NN 1024
#define KNN 20

typedef __attribute__((ext_vector_type(8))) short bf16x8;   // 8 bf16 (4 VGPRs)
typedef __attribute__((ext_vector_type(4))) float f32x4;

__device__ __forceinline__ unsigned short f2b(float f){
    __hip_bfloat16 h = __float2bfloat16(f);
    return *(unsigned short*)&h;
}

// ---------------- fallback: encode ws_size into output if workspace too small ----------------
__global__ void fallback_k(float* __restrict__ out, int n, float c){
    int i = blockIdx.x*256 + threadIdx.x;
    if(i < n) out[i] = c;
}

// ---------------- transpose x [16,1024,3] -> hT [16][3][1024] + sqnorm (same fma chain) --------
__global__ void transpose3s_k(const float* __restrict__ x, float* __restrict__ hT,
                              float* __restrict__ sqn){
    int i = blockIdx.x*256 + threadIdx.x;
    if(i < BB*NN){
        int b = i >> 10, n = i & 1023;
        float s = 0.f;
        #pragma unroll
        for(int d=0; d<3; d++){
            float v = x[(size_t)i*3 + d];
            hT[((size_t)b*3 + d)*NN + n] = v;
            s = fmaf(v, v, s);
        }
        sqn[i] = s;
    }
}

// ---------------- transpose hs slice -> hT [16][D][1024] + sqnorm (ascending-d chain) ----------
template<int D>
__global__ __launch_bounds__(256) void transq_k(const float* __restrict__ src,
                                                float* __restrict__ hT,
                                                float* __restrict__ sqn){
    int nt = blockIdx.x, b = blockIdx.y;
    int tid = threadIdx.x;
    __shared__ float tile[64][65];
    int n0 = nt*64;
    float s = 0.f;
    for(int ct=0; ct<D/64; ct++){
        int c0 = ct*64;
        if(ct) __syncthreads();
        for(int l=tid; l<64*64; l+=256){
            int r = l>>6, c = l&63;
            tile[r][c] = src[(size_t)(b*NN + n0 + r)*512 + c0 + c];
        }
        __syncthreads();
        for(int l=tid; l<64*64; l+=256){
            int d = l>>6, n = l&63;
            hT[((size_t)b*D + c0 + d)*NN + n0 + n] = tile[n][d];
        }
        if(tid < 64){
            for(int c=0;c<64;c++){ float v = tile[tid][c]; s = fmaf(v, v, s); }
        }
    }
    if(tid < 64) sqn[b*NN + n0 + tid] = s;
}

// ---------------- FUSED: knn (dist-GEMM + u32-tournament top-20) || featTU fp32 GEMM -----------
// knn path + feat path: verbatim round 17 (596 µs baseline; r18's [k][row] feat staging
// regressed via 2.4e6 LDS store conflicts — reverted).
template<int D, int O>
__global__ __launch_bounds__(256, 4) void knnfeat_k(const float* __restrict__ hT,
                                                    const float* __restrict__ sqn,
                                                    int* __restrict__ idx,
                                                    const float* __restrict__ h, int S,
                                                    const float* __restrict__ th,
                                                    const float* __restrict__ ph,
                                                    float* __restrict__ T,
                                                    float* __restrict__ hsU){
    constexpr int F = (O/64)*256;     // feat blocks
    constexpr int R = 2048/F;         // knn blocks per feat block
    constexpr int G = R + 1;
    constexpr int SM_KNN  = 32768 + D*32 + 32;
    constexpr int SM_FEAT = 25344;
    constexpr int SM = SM_KNN > SM_FEAT ? SM_KNN : SM_FEAT;
    __shared__ __align__(16) char smem[SM];
    const int tid = threadIdx.x;

    const int bq = blockIdx.x / G;
    const int br = blockIdx.x % G;

    if(br != R){
        // ================= knn path =================
        const int kid  = bq*R + br;
        const int b    = kid >> 7;
        const int n0   = (kid & 127) * 8;
        const int lane = tid & 63;
        const int wv   = tid >> 6;

        float4* distb4 = (float4*)smem;
        float*  rowsA  = (float*)(smem + 32768);
        float*  sqnA   = (float*)(smem + 32768 + D*32);

        const float* hTb = hT + (size_t)b*D*NN;
        for(int l=tid; l<8*D; l+=256){
            int d = l >> 3, r = l & 7;
            rowsA[l] = hTb[(size_t)d*NN + n0 + r];
        }
        if(tid < 8) sqnA[tid] = sqn[b*NN + n0 + tid];
        __syncthreads();

        const int c4 = wv*64 + lane;
        const float4* B4 = (const float4*)hTb;
        float4 acc[8];
        #pragma unroll
        for(int r=0;r<8;r++) acc[r] = make_float4(0.f,0.f,0.f,0.f);

        #pragma unroll 4
        for(int d=0; d<D; d++){
            float4 bv = B4[d*256 + c4];
            float4 a0 = *(const float4*)&rowsA[d*8];
            float4 a1 = *(const float4*)&rowsA[d*8 + 4];
            float ar[8] = {a0.x,a0.y,a0.z,a0.w,a1.x,a1.y,a1.z,a1.w};
            #pragma unroll
            for(int r=0;r<8;r++){
                acc[r].x = fmaf(ar[r], bv.x, acc[r].x);
                acc[r].y = fmaf(ar[r], bv.y, acc[r].y);
                acc[r].z = fmaf(ar[r], bv.z, acc[r].z);
                acc[r].w = fmaf(ar[r], bv.w, acc[r].w);
            }
        }

        float4 sq4 = ((const float4*)(sqn + b*NN))[c4];
        #pragma unroll
        for(int r=0;r<8;r++){
            float sa = sqnA[r];
            float4 dv;
            dv.x = sa + sq4.x - 2.f*acc[r].x;
            dv.y = sa + sq4.y - 2.f*acc[r].y;
            dv.z = sa + sq4.z - 2.f*acc[r].z;
            dv.w = sa + sq4.w - 2.f*acc[r].w;
            distb4[r*256 + c4] = dv;
        }
        __syncthreads();

        // ---- top-20 for rows 2wv, 2wv+1: tournaments interleaved (ILP-2) ----
        const int r0 = 2*wv, r1 = 2*wv + 1;
        unsigned s0[16], s1[16];
        {
            const float4* p0 = &distb4[r0*256];
            const float4* p1 = &distb4[r1*256];
            #pragma unroll
            for(int q4=0;q4<4;q4++){
                float4 f0 = p0[lane + 64*q4];
                float4 f1 = p1[lane + 64*q4];
                float v0[4]={f0.x,f0.y,f0.z,f0.w}, v1[4]={f1.x,f1.y,f1.z,f1.w};
                #pragma unroll
                for(int c=0;c<4;c++){
                    unsigned u0=__float_as_uint(v0[c]); u0 ^= (unsigned)((int)u0>>31)|0x80000000u;
                    unsigned u1=__float_as_uint(v1[c]); u1 ^= (unsigned)((int)u1>>31)|0x80000000u;
                    s0[q4*4+c]=(u0&0xFFFFFFF0u)|(unsigned)(q4*4+c);
                    s1[q4*4+c]=(u1&0xFFFFFFF0u)|(unsigned)(q4*4+c);
                }
            }
        }
        // bitonic sort ascending, both rows interleaved (registers only)
        #pragma unroll
        for(int k=2;k<=16;k<<=1){
            #pragma unroll
            for(int j=k>>1;j>0;j>>=1){
                #pragma unroll
                for(int i=0;i<16;i++){
                    int l = i ^ j;
                    if(l > i){
                        bool up = ((i & k) == 0);
                        unsigned a, b2, lo, hi;
                        a=s0[i]; b2=s0[l]; lo=a<b2?a:b2; hi=a<b2?b2:a; s0[i]=up?lo:hi; s0[l]=up?hi:lo;
                        a=s1[i]; b2=s1[l]; lo=a<b2?a:b2; hi=a<b2?b2:a; s1[i]=up?lo:hi; s1[l]=up?hi:lo;
                    }
                }
            }
        }
        // q-major dump into the dead dist rows (conflict-free)
        unsigned* sb0 = (unsigned*)distb4 + r0*1024;
        unsigned* sb1 = (unsigned*)distb4 + r1*1024;
        #pragma unroll
        for(int q=0;q<16;q++){ sb0[q*64 + lane] = s0[q]; sb1[q*64 + lane] = s1[q]; }

        int cnt0 = 0, cnt1 = 0;
        unsigned cur0 = (s0[0] & 0xFFFFFFC0u) | (unsigned)lane;
        unsigned cur1 = (s1[0] & 0xFFFFFFC0u) | (unsigned)lane;
        int q00 = s0[0] & 15, q10 = s1[0] & 15;
        int g0v = 4*lane + 256*(q00>>2) + (q00&3);
        int g1v = 4*lane + 256*(q10>>2) + (q10&3);
        int* out0 = idx + ((size_t)b*NN + n0 + r0)*KNN;
        int* out1 = idx + ((size_t)b*NN + n0 + r1)*KNN;
        for(int t=0;t<KNN;t++){
            unsigned w0 = cur0, w1 = cur1;
            #pragma unroll
            for(int off=32; off>0; off>>=1){
                unsigned o0 = __shfl_xor(w0, off);
                unsigned o1 = __shfl_xor(w1, off);
                w0 = w0 < o0 ? w0 : o0;
                w1 = w1 < o1 ? w1 : o1;
            }
            int g0 = __shfl(g0v, (int)(w0 & 63));
            int g1 = __shfl(g1v, (int)(w1 & 63));
            if(lane == 0){ out0[t] = g0; out1[t] = g1; }
            if(w0 == cur0){
                cnt0++;
                unsigned hn = sb0[(cnt0 & 15)*64 + lane];
                if(cnt0 >= 16) hn = 0xFFFFFFFFu;
                int q = hn & 15; g0v = 4*lane + 256*(q>>2) + (q&3);
                cur0 = (hn & 0xFFFFFFC0u) | (unsigned)lane;
            }
            if(w1 == cur1){
                cnt1++;
                unsigned hn = sb1[(cnt1 & 15)*64 + lane];
                if(cnt1 >= 16) hn = 0xFFFFFFFFu;
                int q = hn & 15; g1v = 4*lane + 256*(q>>2) + (q&3);
                cur1 = (hn & 0xFFFFFFC0u) | (unsigned)lane;
            }
        }
    } else {
        // ================= featTU path (fp32 VALU — precision-critical, feeds kNN) ============
        int fid = bq;
        int ot = fid % (O/64);
        int nt = fid / (O/64);
        int tx = tid & 15, ty = tid >> 4;
        float (*As)[33] = (float(*)[33])(smem);
        float (*Wt)[33] = (float(*)[33])(smem + 8448);
        float (*Wp)[33] = (float(*)[33])(smem + 16896);
        float acct[4][4] = {};
        float accp[4][4] = {};
        for(int kk=0; kk<D; kk+=32){
            if(kk) __syncthreads();
            for(int l=tid; l<64*32; l+=256){
                int r = l>>5, c = l&31, d = kk + c;
                As[r][c] = (d < D) ? h[(size_t)(nt*64+r)*S + d] : 0.f;
                Wt[r][c] = (d < D) ? th[(size_t)(ot*64+r)*D + d] : 0.f;
                Wp[r][c] = (d < D) ? ph[(size_t)(ot*64+r)*D + d] : 0.f;
            }
            __syncthreads();
            #pragma unroll
            for(int k=0;k<32;k++){
                float a[4], bt[4], bp[4];
                #pragma unroll
                for(int i=0;i<4;i++) a[i]  = As[ty+16*i][k];
                #pragma unroll
                for(int j=0;j<4;j++){ bt[j] = Wt[tx+16*j][k]; bp[j] = Wp[tx+16*j][k]; }
                #pragma unroll
                for(int i=0;i<4;i++)
                    #pragma unroll
                    for(int j=0;j<4;j++){
                        acct[i][j] = fmaf(a[i], bt[j], acct[i][j]);
                        accp[i][j] = fmaf(a[i], bp[j], accp[i][j]);
                    }
            }
        }
        #pragma unroll
        for(int i=0;i<4;i++){
            int rw = nt*64 + ty + 16*i;
            #pragma unroll
            for(int j=0;j<4;j++){
                int o = ot*64 + tx + 16*j;
                T[(size_t)rw*O + o]    = acct[i][j];
                hsU[(size_t)rw*512 + o] = accp[i][j] - acct[i][j];   // U -> hs out-slice
            }
        }
    }
}

// ---------------- gather 20 neighbors of T, max, + U (in-place in hs slice), leaky -------------
template<int O>
__global__ __launch_bounds__(256) void gather2_k(const float* __restrict__ T,
                                                 const int* __restrict__ idx,
                                                 float* __restrict__ outp){
    constexpr int P = 256 / O;           // points per block
    int bn0 = blockIdx.x * P;
    int tid = threadIdx.x;
    int p = tid / O, o = tid % O;
    int bn = bn0 + p;
    int b  = bn >> 10;
    __shared__ int nb[P*KNN];
    if(tid < P*KNN){
        int pp = tid / KNN, k = tid % KNN;
        nb[pp*KNN + k] = idx[(size_t)(bn0+pp)*KNN + k] & (NN-1);  // mask: never faults
    }
    __syncthreads();
    const float* Tb = T + (size_t)b*NN*O;
    float m = -3.402823466e38f;
    #pragma unroll
    for(int k=0;k<KNN;k++) m = fmaxf(m, Tb[(size_t)nb[p*KNN+k]*O + o]);
    float v = m + outp[(size_t)bn*512 + o];      // U was staged here by knnfeat
    v = (v > 0.f) ? v : 0.2f*v;
    outp[(size_t)bn*512 + o] = v;
}

// ---------------- merged casts: hs [16384,512] f32->bf16 and proj_w [1024,512] f32->bf16 -------
__global__ __launch_bounds__(256) void castall_k(const float* __restrict__ hs, unsigned short* __restrict__ hb,
                                                 const float* __restrict__ w, unsigned short* __restrict__ wb){
    const float4* in4;
    unsigned short* dst;
    int i;
    if(blockIdx.x < 4096){ i = blockIdx.x*256 + threadIdx.x; in4 = (const float4*)hs; dst = hb; }
    else                 { i = (blockIdx.x-4096)*256 + threadIdx.x; in4 = (const float4*)w;  dst = wb; }
    float4 a = in4[2*i], c = in4[2*i+1];
    unsigned short t[8];
    t[0]=f2b(a.x); t[1]=f2b(a.y); t[2]=f2b(a.z); t[3]=f2b(a.w);
    t[4]=f2b(c.x); t[5]=f2b(c.y); t[6]=f2b(c.z); t[7]=f2b(c.w);
    *(ulonglong2*)&dst[8*i] = *(ulonglong2*)t;
}

// ---------------- projection GEMM via bf16 MFMA: 128x128 tile, BK=64 (half the barriers) -------
// MFMA order per accumulator unchanged (k ascending: ko=0 group then ko=32) -> bit-identical.
__global__ __launch_bounds__(256) void proj3_k(const unsigned short* __restrict__ hsb,
                                               const unsigned short* __restrict__ wb,
                                               float* __restrict__ pmax){
    int bi = blockIdx.x;
    int ot = bi >> 7;             // col tile (0..7) in high bits -> A-tile sharers on same XCD
    int nb = bi & 127;
    int b  = nb >> 3, nt = nb & 7;
    int tid = threadIdx.x, lane = tid & 63, wv = tid >> 6;
    int quad = lane >> 4, m = lane & 15;

    __shared__ __align__(16) unsigned short Ab[128*72];   // row stride 72 bf16 = 144 B
    __shared__ __align__(16) unsigned short Bb[128*72];

    f32x4 acc[8][2] = {};
    const unsigned short* ha = hsb + ((size_t)(b*NN + nt*128))*512;
    const unsigned short* wa = wb + (size_t)ot*128*512;

    for(int kk=0; kk<512; kk+=64){
        __syncthreads();
        #pragma unroll
        for(int q=0; q<4; q++){
            int idx = tid + 256*q;          // 1024 segs: r=idx>>3 (128 rows), sg=idx&7 (8 bf16 each)
            int r = idx >> 3, sg = idx & 7;
            ulonglong2 va = *(const ulonglong2*)&ha[(size_t)r*512 + kk + sg*8];
            ulonglong2 vw = *(const ulonglong2*)&wa[(size_t)r*512 + kk + sg*8];
            *(ulonglong2*)&Ab[r*72 + sg*8] = va;
            *(ulonglong2*)&Bb[r*72 + sg*8] = vw;
        }
        __syncthreads();
        #pragma unroll
        for(int ko=0; ko<64; ko+=32){
            bf16x8 bf0 = *(bf16x8*)&Bb[(wv*32 + m)*72 + ko + quad*8];
            bf16x8 bf1 = *(bf16x8*)&Bb[(wv*32 + 16 + m)*72 + ko + quad*8];
            #pragma unroll
            for(int rt=0; rt<8; rt++){
                bf16x8 af = *(bf16x8*)&Ab[(rt*16 + m)*72 + ko + quad*8];
                acc[rt][0] = __builtin_amdgcn_mfma_f32_16x16x32_bf16(af, bf0, acc[rt][0], 0,0,0);
                acc[rt][1] = __builtin_amdgcn_mfma_f32_16x16x32_bf16(af, bf1, acc[rt][1], 0,0,0);
            }
        }
    }

    #pragma unroll
    for(int ct=0; ct<2; ct++){
        float mx = acc[0][ct][0];
        #pragma unroll
        for(int rt=0; rt<8; rt++)
            #pragma unroll
            for(int r=0; r<4; r++) mx = fmaxf(mx, acc[rt][ct][r]);
        mx = fmaxf(mx, __shfl_xor(mx, 16));
        mx = fmaxf(mx, __shfl_xor(mx, 32));
        if(quad == 0)
            pmax[((size_t)b*8 + nt)*1024 + ot*128 + wv*32 + ct*16 + m] = mx;
    }
}

// ---------------- column sums of hs: colsum[16][512] (for algebraic mean-pool, fp32) ----------------
__global__ void colsum_k(const float* __restrict__ hs, float* __restrict__ colsum){
    int i = blockIdx.x*256 + threadIdx.x;   // b*512 + c
    if(i >= BB*512) return;
    int b = i >> 9, c = i & 511;
    const float* p = hs + (size_t)b*NN*512 + c;
    float s = 0.f;
    for(int n=0;n<NN;n++) s += p[(size_t)n*512];
    colsum[i] = s;
}

// ---------------- combine: max over 8 tiles; mean = colsum@w/1024 (fp32); + bias ----------------
__global__ __launch_bounds__(256) void pool_final2_k(const float* __restrict__ pmax,
                                                     const float* __restrict__ colsum,
                                                     const float* __restrict__ w,
                                                     const float* __restrict__ pb,
                                                     float* __restrict__ pooled){
    int i = blockIdx.x*256 + threadIdx.x;   // b*1024 + o
    int b = i >> 10, o = i & 1023;
    __shared__ float cs[512];
    for(int l=threadIdx.x; l<512; l+=256) cs[l] = colsum[b*512 + l];
    __syncthreads();
    float m = -3.402823466e38f;
    #pragma unroll
    for(int t=0;t<8;t++) m = fmaxf(m, pmax[((size_t)b*8 + t)*1024 + o]);
    float s = 0.f;
    const float4* w4 = (const float4*)(w + (size_t)o*512);
    const float4* c4 = (const float4*)cs;
    for(int d=0; d<128; d++){
        float4 wv = w4[d]; float4 cv = c4[d];
        s = fmaf(cv.x, wv.x, s); s = fmaf(cv.y, wv.y, s);
        s = fmaf(cv.z, wv.z, s); s = fmaf(cv.w, wv.w, s);
    }
    float bias = pb[o];
    pooled[b*2048 + o]        = m + bias;
    pooled[b*2048 + 1024 + o] = s * (1.f/1024.f) + bias;
}

// ---------------- head FC + BatchNorm(batch of 16) + leaky; one block per feature ----------------
template<int IN>
__global__ __launch_bounds__(256) void head_bn_k(const float* __restrict__ in, const float* __restrict__ w,
                                                 const float* __restrict__ bias, const float* __restrict__ g,
                                                 const float* __restrict__ bt, float* __restrict__ out, int OUT){
    int o = blockIdx.x;
    int tid = threadIdx.x, bb = tid >> 4, s = tid & 15;
    const float* ir = in + (size_t)bb*IN;
    const float* wr = w  + (size_t)o*IN;
    float acc = 0.f;
    for(int d=s; d<IN; d+=16) acc = fmaf(ir[d], wr[d], acc);
    #pragma unroll
    for(int off=8; off>0; off>>=1) acc += __shfl_xor(acc, off);
    __shared__ float vals[16];
    __shared__ float stats[2];
    if(s == 0) vals[bb] = acc + bias[o];
    __syncthreads();
    if(tid == 0){
        float mu = 0.f;
        for(int q=0;q<16;q++) mu += vals[q];
        mu *= (1.f/16.f);
        float var = 0.f;
        for(int q=0;q<16;q++){ float d = vals[q]-mu; var = fmaf(d,d,var); }
        var *= (1.f/16.f);
        stats[0] = mu; stats[1] = rsqrtf(var + 1e-5f);
    }
    __syncthreads();
    if(s == 0){
        float v = (vals[bb]-stats[0])*stats[1]*g[o] + bt[o];
        v = (v > 0.f) ? v : 0.2f*v;
        out[(size_t)bb*OUT + o] = v;
    }
}

// ---------------- final linear -> f32 out [16,40] ----------------
__global__ __launch_bounds__(256) void head_out_k(const float* __restrict__ in, const float* __restrict__ w,
                                                  const float* __restrict__ bias, float* __restrict__ out){
    int o = blockIdx.x;   // 40
    int tid = threadIdx.x, bb = tid >> 4, s = tid & 15;
    const float* ir = in + (size_t)bb*256;
    float acc = 0.f;
    for(int d=s; d<256; d+=16) acc = fmaf(ir[d], w[o*256+d], acc);
    #pragma unroll
    for(int off=8; off>0; off>>=1) acc += __shfl_xor(acc, off);
    if(s == 0) out[bb*40 + o] = acc + bias[o];
}

extern "C" void kernel_launch(void* const* d_in, const int* in_sizes, int n_in,
                              void* d_out, int out_size, void* d_ws, size_t ws_size,
                              hipStream_t stream) {
    const float* x       = (const float*)d_in[0];
    const float* th[4]   = {(const float*)d_in[1], (const float*)d_in[3], (const float*)d_in[5], (const float*)d_in[7]};
    const float* ph[4]   = {(const float*)d_in[2], (const float*)d_in[4], (const float*)d_in[6], (const float*)d_in[8]};
    const float* proj_w  = (const float*)d_in[9];
    const float* proj_b  = (const float*)d_in[10];
    const float* emb0_w  = (const float*)d_in[11];
    const float* emb0_b  = (const float*)d_in[12];
    const float* bn0_g   = (const float*)d_in[13];
    const float* bn0_b   = (const float*)d_in[14];
    const float* emb1_w  = (const float*)d_in[15];
    const float* emb1_b  = (const float*)d_in[16];
    const float* bn1_g   = (const float*)d_in[17];
    const float* bn1_b   = (const float*)d_in[18];
    const float* out_w   = (const float*)d_in[19];
    const float* out_b   = (const float*)d_in[20];
    float* outp = (float*)d_out;

    // workspace layout (float elements) — REQ unchanged (guard passed at 68.5 MB)
    const size_t OFF_HS  = 0;                       // 16384 x 512 = 8,388,608
    const size_t OFF_T   = 8388608;                 // T outputs (4,194,304)
    const size_t OFF_U   = 12582912;                // hT (<=2,097,152) then hsbf
    const size_t OFF_SQN = 16777216;                // 16384
    const size_t OFF_IDX = 16793600;                // 16384 x 20 ints = 327,680
    const size_t REQ_FL  = 17121280;
    const size_t REQ     = REQ_FL * 4;              // 68,485,120 bytes

    if(ws_size < REQ){
        fallback_k<<<(out_size+255)/256, 256, 0, stream>>>(outp, out_size, (float)((double)ws_size*1e-6));
        return;
    }

    float* Wf   = (float*)d_ws;
    float* hs   = Wf + OFF_HS;
    float* T    = Wf + OFF_T;
    float* hT   = Wf + OFF_U;                       // hT in old U region (no T alias)
    float* sqn  = Wf + OFF_SQN;
    int*   idxb = (int*)(Wf + OFF_IDX);
    // post-layer aliases (T region dead after last gather):
    float* pmax   = T;                                  // 131,072 fl
    float* colsum = T + 131072;
    float* pooled = T + 147456;
    float* z0     = T + 180224;
    float* z1     = T + 188416;
    unsigned short* wbf  = (unsigned short*)(T + 200704);   // 524,288 bf16 (inside T region)
    unsigned short* hsbf = (unsigned short*)(Wf + OFF_U);   // old U region (hT dead after layer 3)

    // ---- layer 0: h=x (S=3,D=3) -> O=64 at hs ch 0     (grid = 2048 knn + 256 feat, interleaved)
    transpose3s_k<<<64,256,0,stream>>>(x, hT, sqn);
    knnfeat_k<3,64><<<2304,256,0,stream>>>(hT, sqn, idxb, x, 3, th[0], ph[0], T, hs + 0);
    gather2_k<64><<<BB*NN/4,256,0,stream>>>(T, idxb, hs + 0);

    // ---- layer 1: h=hs[:,0:64] (S=512,D=64) -> O=64 at ch 64
    transq_k<64><<<dim3(16,16),256,0,stream>>>(hs + 0, hT, sqn);
    knnfeat_k<64,64><<<2304,256,0,stream>>>(hT, sqn, idxb, hs + 0, 512, th[1], ph[1], T, hs + 64);
    gather2_k<64><<<BB*NN/4,256,0,stream>>>(T, idxb, hs + 64);

    // ---- layer 2: h=hs[:,64:128] (D=64) -> O=128 at ch 128   (2048 + 512)
    transq_k<64><<<dim3(16,16),256,0,stream>>>(hs + 64, hT, sqn);
    knnfeat_k<64,128><<<2560,256,0,stream>>>(hT, sqn, idxb, hs + 64, 512, th[2], ph[2], T, hs + 128);
    gather2_k<128><<<BB*NN/2,256,0,stream>>>(T, idxb, hs + 128);

    // ---- layer 3: h=hs[:,128:256] (D=128) -> O=256 at ch 256  (2048 + 1024)
    transq_k<128><<<dim3(16,16),256,0,stream>>>(hs + 128, hT, sqn);
    knnfeat_k<128,256><<<3072,256,0,stream>>>(hT, sqn, idxb, hs + 128, 512, th[3], ph[3], T, hs + 256);
    gather2_k<256><<<BB*NN,256,0,stream>>>(T, idxb, hs + 256);

    // ---- casts (hT dead; hsbf reuses that region; wbf corner of T region)
    castall_k<<<4096+256,256,0,stream>>>(hs, hsbf, proj_w, wbf);

    // ---- projection + pooling (max via bf16 MFMA GEMM; mean via fp32 colsum @ w)
    proj3_k<<<1024,256,0,stream>>>(hsbf, wbf, pmax);
    colsum_k<<<32,256,0,stream>>>(hs, colsum);
    pool_final2_k<<<64,256,0,stream>>>(pmax, colsum, proj_w, proj_b, pooled);

    // ---- head
    head_bn_k<2048><<<512,256,0,stream>>>(pooled, emb0_w, emb0_b, bn0_g, bn0_b, z0, 512);
    head_bn_k<512><<<256,256,0,stream>>>(z0, emb1_w, emb1_b, bn1_g, bn1_b, z1, 256);
    head_out_k<<<40,256,0,stream>>>(z1, out_w, out_b, outp);
}

// Round 20
// 593.825 us; speedup vs baseline: 1.0531x; 1.0243x over previous
//
#include <hip/hip_runtime.h>
#include <hip/hip_bf16.h>

#define BB 16
#define NN 1024
#define KNN 20

typedef __attribute__((ext_vector_type(8))) short bf16x8;   // 8 bf16 (4 VGPRs)
typedef __attribute__((ext_vector_type(4))) float f32x4;

__device__ __forceinline__ unsigned short f2b(float f){
    __hip_bfloat16 h = __float2bfloat16(f);
    return *(unsigned short*)&h;
}

// ---------------- fallback: encode ws_size into output if workspace too small ----------------
__global__ void fallback_k(float* __restrict__ out, int n, float c){
    int i = blockIdx.x*256 + threadIdx.x;
    if(i < n) out[i] = c;
}

// ---------------- transpose x [16,1024,3] -> hT [16][3][1024] + sqnorm (same fma chain) --------
__global__ void transpose3s_k(const float* __restrict__ x, float* __restrict__ hT,
                              float* __restrict__ sqn){
    int i = blockIdx.x*256 + threadIdx.x;
    if(i < BB*NN){
        int b = i >> 10, n = i & 1023;
        float s = 0.f;
        #pragma unroll
        for(int d=0; d<3; d++){
            float v = x[(size_t)i*3 + d];
            hT[((size_t)b*3 + d)*NN + n] = v;
            s = fmaf(v, v, s);
        }
        sqn[i] = s;
    }
}

// ---------------- transpose hs slice -> hT [16][D][1024] + sqnorm (ascending-d chain) ----------
template<int D>
__global__ __launch_bounds__(256) void transq_k(const float* __restrict__ src,
                                                float* __restrict__ hT,
                                                float* __restrict__ sqn){
    int nt = blockIdx.x, b = blockIdx.y;
    int tid = threadIdx.x;
    __shared__ float tile[64][65];
    int n0 = nt*64;
    float s = 0.f;
    for(int ct=0; ct<D/64; ct++){
        int c0 = ct*64;
        if(ct) __syncthreads();
        for(int l=tid; l<64*64; l+=256){
            int r = l>>6, c = l&63;
            tile[r][c] = src[(size_t)(b*NN + n0 + r)*512 + c0 + c];
        }
        __syncthreads();
        for(int l=tid; l<64*64; l+=256){
            int d = l>>6, n = l&63;
            hT[((size_t)b*D + c0 + d)*NN + n0 + n] = tile[n][d];
        }
        if(tid < 64){
            for(int c=0;c<64;c++){ float v = tile[tid][c]; s = fmaf(v, v, s); }
        }
    }
    if(tid < 64) sqn[b*NN + n0 + tid] = s;
}

// ---------------- FUSED: knn (dist-GEMM + u32-tournament top-20) || featTU fp32 GEMM -----------
// Both paths verbatim round 17 (the 596 µs best): knn indices bit-identical; feat fp32
// (precision-critical — hs must stay <=2^-19-accurate; bf16-class feat broke kNN in r16).
template<int D, int O>
__global__ __launch_bounds__(256, 4) void knnfeat_k(const float* __restrict__ hT,
                                                    const float* __restrict__ sqn,
                                                    int* __restrict__ idx,
                                                    const float* __restrict__ h, int S,
                                                    const float* __restrict__ th,
                                                    const float* __restrict__ ph,
                                                    float* __restrict__ T,
                                                    float* __restrict__ hsU){
    constexpr int F = (O/64)*256;     // feat blocks
    constexpr int R = 2048/F;         // knn blocks per feat block
    constexpr int G = R + 1;
    constexpr int SM_KNN  = 32768 + D*32 + 32;
    constexpr int SM_FEAT = 25344;
    constexpr int SM = SM_KNN > SM_FEAT ? SM_KNN : SM_FEAT;
    __shared__ __align__(16) char smem[SM];
    const int tid = threadIdx.x;

    const int bq = blockIdx.x / G;
    const int br = blockIdx.x % G;

    if(br != R){
        // ================= knn path =================
        const int kid  = bq*R + br;
        const int b    = kid >> 7;
        const int n0   = (kid & 127) * 8;
        const int lane = tid & 63;
        const int wv   = tid >> 6;

        float4* distb4 = (float4*)smem;
        float*  rowsA  = (float*)(smem + 32768);
        float*  sqnA   = (float*)(smem + 32768 + D*32);

        const float* hTb = hT + (size_t)b*D*NN;
        for(int l=tid; l<8*D; l+=256){
            int d = l >> 3, r = l & 7;
            rowsA[l] = hTb[(size_t)d*NN + n0 + r];
        }
        if(tid < 8) sqnA[tid] = sqn[b*NN + n0 + tid];
        __syncthreads();

        const int c4 = wv*64 + lane;
        const float4* B4 = (const float4*)hTb;
        float4 acc[8];
        #pragma unroll
        for(int r=0;r<8;r++) acc[r] = make_float4(0.f,0.f,0.f,0.f);

        #pragma unroll 4
        for(int d=0; d<D; d++){
            float4 bv = B4[d*256 + c4];
            float4 a0 = *(const float4*)&rowsA[d*8];
            float4 a1 = *(const float4*)&rowsA[d*8 + 4];
            float ar[8] = {a0.x,a0.y,a0.z,a0.w,a1.x,a1.y,a1.z,a1.w};
            #pragma unroll
            for(int r=0;r<8;r++){
                acc[r].x = fmaf(ar[r], bv.x, acc[r].x);
                acc[r].y = fmaf(ar[r], bv.y, acc[r].y);
                acc[r].z = fmaf(ar[r], bv.z, acc[r].z);
                acc[r].w = fmaf(ar[r], bv.w, acc[r].w);
            }
        }

        float4 sq4 = ((const float4*)(sqn + b*NN))[c4];
        #pragma unroll
        for(int r=0;r<8;r++){
            float sa = sqnA[r];
            float4 dv;
            dv.x = sa + sq4.x - 2.f*acc[r].x;
            dv.y = sa + sq4.y - 2.f*acc[r].y;
            dv.z = sa + sq4.z - 2.f*acc[r].z;
            dv.w = sa + sq4.w - 2.f*acc[r].w;
            distb4[r*256 + c4] = dv;
        }
        __syncthreads();

        // ---- top-20 for rows 2wv, 2wv+1: tournaments interleaved (ILP-2) ----
        const int r0 = 2*wv, r1 = 2*wv + 1;
        unsigned s0[16], s1[16];
        {
            const float4* p0 = &distb4[r0*256];
            const float4* p1 = &distb4[r1*256];
            #pragma unroll
            for(int q4=0;q4<4;q4++){
                float4 f0 = p0[lane + 64*q4];
                float4 f1 = p1[lane + 64*q4];
                float v0[4]={f0.x,f0.y,f0.z,f0.w}, v1[4]={f1.x,f1.y,f1.z,f1.w};
                #pragma unroll
                for(int c=0;c<4;c++){
                    unsigned u0=__float_as_uint(v0[c]); u0 ^= (unsigned)((int)u0>>31)|0x80000000u;
                    unsigned u1=__float_as_uint(v1[c]); u1 ^= (unsigned)((int)u1>>31)|0x80000000u;
                    s0[q4*4+c]=(u0&0xFFFFFFF0u)|(unsigned)(q4*4+c);
                    s1[q4*4+c]=(u1&0xFFFFFFF0u)|(unsigned)(q4*4+c);
                }
            }
        }
        // bitonic sort ascending, both rows interleaved (registers only)
        #pragma unroll
        for(int k=2;k<=16;k<<=1){
            #pragma unroll
            for(int j=k>>1;j>0;j>>=1){
                #pragma unroll
                for(int i=0;i<16;i++){
                    int l = i ^ j;
                    if(l > i){
                        bool up = ((i & k) == 0);
                        unsigned a, b2, lo, hi;
                        a=s0[i]; b2=s0[l]; lo=a<b2?a:b2; hi=a<b2?b2:a; s0[i]=up?lo:hi; s0[l]=up?hi:lo;
                        a=s1[i]; b2=s1[l]; lo=a<b2?a:b2; hi=a<b2?b2:a; s1[i]=up?lo:hi; s1[l]=up?hi:lo;
                    }
                }
            }
        }
        // q-major dump into the dead dist rows (conflict-free)
        unsigned* sb0 = (unsigned*)distb4 + r0*1024;
        unsigned* sb1 = (unsigned*)distb4 + r1*1024;
        #pragma unroll
        for(int q=0;q<16;q++){ sb0[q*64 + lane] = s0[q]; sb1[q*64 + lane] = s1[q]; }

        int cnt0 = 0, cnt1 = 0;
        unsigned cur0 = (s0[0] & 0xFFFFFFC0u) | (unsigned)lane;
        unsigned cur1 = (s1[0] & 0xFFFFFFC0u) | (unsigned)lane;
        int q00 = s0[0] & 15, q10 = s1[0] & 15;
        int g0v = 4*lane + 256*(q00>>2) + (q00&3);
        int g1v = 4*lane + 256*(q10>>2) + (q10&3);
        int* out0 = idx + ((size_t)b*NN + n0 + r0)*KNN;
        int* out1 = idx + ((size_t)b*NN + n0 + r1)*KNN;
        for(int t=0;t<KNN;t++){
            unsigned w0 = cur0, w1 = cur1;
            #pragma unroll
            for(int off=32; off>0; off>>=1){
                unsigned o0 = __shfl_xor(w0, off);
                unsigned o1 = __shfl_xor(w1, off);
                w0 = w0 < o0 ? w0 : o0;
                w1 = w1 < o1 ? w1 : o1;
            }
            int g0 = __shfl(g0v, (int)(w0 & 63));
            int g1 = __shfl(g1v, (int)(w1 & 63));
            if(lane == 0){ out0[t] = g0; out1[t] = g1; }
            if(w0 == cur0){
                cnt0++;
                unsigned hn = sb0[(cnt0 & 15)*64 + lane];
                if(cnt0 >= 16) hn = 0xFFFFFFFFu;
                int q = hn & 15; g0v = 4*lane + 256*(q>>2) + (q&3);
                cur0 = (hn & 0xFFFFFFC0u) | (unsigned)lane;
            }
            if(w1 == cur1){
                cnt1++;
                unsigned hn = sb1[(cnt1 & 15)*64 + lane];
                if(cnt1 >= 16) hn = 0xFFFFFFFFu;
                int q = hn & 15; g1v = 4*lane + 256*(q>>2) + (q&3);
                cur1 = (hn & 0xFFFFFFC0u) | (unsigned)lane;
            }
        }
    } else {
        // ================= featTU path (fp32 VALU — precision-critical, feeds kNN) ============
        int fid = bq;
        int ot = fid % (O/64);
        int nt = fid / (O/64);
        int tx = tid & 15, ty = tid >> 4;
        float (*As)[33] = (float(*)[33])(smem);
        float (*Wt)[33] = (float(*)[33])(smem + 8448);
        float (*Wp)[33] = (float(*)[33])(smem + 16896);
        float acct[4][4] = {};
        float accp[4][4] = {};
        for(int kk=0; kk<D; kk+=32){
            if(kk) __syncthreads();
            for(int l=tid; l<64*32; l+=256){
                int r = l>>5, c = l&31, d = kk + c;
                As[r][c] = (d < D) ? h[(size_t)(nt*64+r)*S + d] : 0.f;
                Wt[r][c] = (d < D) ? th[(size_t)(ot*64+r)*D + d] : 0.f;
                Wp[r][c] = (d < D) ? ph[(size_t)(ot*64+r)*D + d] : 0.f;
            }
            __syncthreads();
            #pragma unroll
            for(int k=0;k<32;k++){
                float a[4], bt[4], bp[4];
                #pragma unroll
                for(int i=0;i<4;i++) a[i]  = As[ty+16*i][k];
                #pragma unroll
                for(int j=0;j<4;j++){ bt[j] = Wt[tx+16*j][k]; bp[j] = Wp[tx+16*j][k]; }
                #pragma unroll
                for(int i=0;i<4;i++)
                    #pragma unroll
                    for(int j=0;j<4;j++){
                        acct[i][j] = fmaf(a[i], bt[j], acct[i][j]);
                        accp[i][j] = fmaf(a[i], bp[j], accp[i][j]);
                    }
            }
        }
        #pragma unroll
        for(int i=0;i<4;i++){
            int rw = nt*64 + ty + 16*i;
            #pragma unroll
            for(int j=0;j<4;j++){
                int o = ot*64 + tx + 16*j;
                T[(size_t)rw*O + o]    = acct[i][j];
                hsU[(size_t)rw*512 + o] = accp[i][j] - acct[i][j];   // U -> hs out-slice
            }
        }
    }
}

// ---------------- gather 20 neighbors of T, max, + U (in-place in hs slice), leaky -------------
template<int O>
__global__ __launch_bounds__(256) void gather2_k(const float* __restrict__ T,
                                                 const int* __restrict__ idx,
                                                 float* __restrict__ outp){
    constexpr int P = 256 / O;           // points per block
    int bn0 = blockIdx.x * P;
    int tid = threadIdx.x;
    int p = tid / O, o = tid % O;
    int bn = bn0 + p;
    int b  = bn >> 10;
    __shared__ int nb[P*KNN];
    if(tid < P*KNN){
        int pp = tid / KNN, k = tid % KNN;
        nb[pp*KNN + k] = idx[(size_t)(bn0+pp)*KNN + k] & (NN-1);  // mask: never faults
    }
    __syncthreads();
    const float* Tb = T + (size_t)b*NN*O;
    float m = -3.402823466e38f;
    #pragma unroll
    for(int k=0;k<KNN;k++) m = fmaxf(m, Tb[(size_t)nb[p*KNN+k]*O + o]);
    float v = m + outp[(size_t)bn*512 + o];      // U was staged here by knnfeat
    v = (v > 0.f) ? v : 0.2f*v;
    outp[(size_t)bn*512 + o] = v;
}

// ---------------- merged casts: hs [16384,512] f32->bf16 and proj_w [1024,512] f32->bf16 -------
__global__ __launch_bounds__(256) void castall_k(const float* __restrict__ hs, unsigned short* __restrict__ hb,
                                                 const float* __restrict__ w, unsigned short* __restrict__ wb){
    const float4* in4;
    unsigned short* dst;
    int i;
    if(blockIdx.x < 4096){ i = blockIdx.x*256 + threadIdx.x; in4 = (const float4*)hs; dst = hb; }
    else                 { i = (blockIdx.x-4096)*256 + threadIdx.x; in4 = (const float4*)w;  dst = wb; }
    float4 a = in4[2*i], c = in4[2*i+1];
    unsigned short t[8];
    t[0]=f2b(a.x); t[1]=f2b(a.y); t[2]=f2b(a.z); t[3]=f2b(a.w);
    t[4]=f2b(c.x); t[5]=f2b(c.y); t[6]=f2b(c.z); t[7]=f2b(c.w);
    *(ulonglong2*)&dst[8*i] = *(ulonglong2*)t;
}

// ---------------- projection GEMM via bf16 MFMA: 128x128 tile, BK=32 (r17 config) --------------
// r19's BK=64 raised LDS 20.5->36.9 KB, dropping occupancy ~7->4 blocks/CU: net -12 µs. Reverted.
__global__ __launch_bounds__(256) void proj3_k(const unsigned short* __restrict__ hsb,
                                               const unsigned short* __restrict__ wb,
                                               float* __restrict__ pmax){
    int bi = blockIdx.x;
    int ot = bi >> 7;             // col tile (0..7) in high bits -> A-tile sharers on same XCD
    int nb = bi & 127;
    int b  = nb >> 3, nt = nb & 7;
    int tid = threadIdx.x, lane = tid & 63, wv = tid >> 6;
    int quad = lane >> 4, m = lane & 15;

    __shared__ __align__(16) unsigned short Ab[128*40];   // row stride 40 bf16 = 80 B
    __shared__ __align__(16) unsigned short Bb[128*40];

    f32x4 acc[8][2] = {};
    const unsigned short* ha = hsb + ((size_t)(b*NN + nt*128))*512;
    const unsigned short* wa = wb + (size_t)ot*128*512;

    for(int kk=0; kk<512; kk+=32){
        __syncthreads();
        #pragma unroll
        for(int q=0; q<2; q++){
            int idx = tid + 256*q;
            int r = idx >> 2, sg = idx & 3;
            ulonglong2 va = *(const ulonglong2*)&ha[(size_t)r*512 + kk + sg*8];
            ulonglong2 vw = *(const ulonglong2*)&wa[(size_t)r*512 + kk + sg*8];
            *(ulonglong2*)&Ab[r*40 + sg*8] = va;
            *(ulonglong2*)&Bb[r*40 + sg*8] = vw;
        }
        __syncthreads();
        bf16x8 bf0 = *(bf16x8*)&Bb[(wv*32 + m)*40 + quad*8];
        bf16x8 bf1 = *(bf16x8*)&Bb[(wv*32 + 16 + m)*40 + quad*8];
        #pragma unroll
        for(int rt=0; rt<8; rt++){
            bf16x8 af = *(bf16x8*)&Ab[(rt*16 + m)*40 + quad*8];
            acc[rt][0] = __builtin_amdgcn_mfma_f32_16x16x32_bf16(af, bf0, acc[rt][0], 0,0,0);
            acc[rt][1] = __builtin_amdgcn_mfma_f32_16x16x32_bf16(af, bf1, acc[rt][1], 0,0,0);
        }
    }

    #pragma unroll
    for(int ct=0; ct<2; ct++){
        float mx = acc[0][ct][0];
        #pragma unroll
        for(int rt=0; rt<8; rt++)
            #pragma unroll
            for(int r=0; r<4; r++) mx = fmaxf(mx, acc[rt][ct][r]);
        mx = fmaxf(mx, __shfl_xor(mx, 16));
        mx = fmaxf(mx, __shfl_xor(mx, 32));
        if(quad == 0)
            pmax[((size_t)b*8 + nt)*1024 + ot*128 + wv*32 + ct*16 + m] = mx;
    }
}

// ---------------- column sums of hs: colsum[16][512] (for algebraic mean-pool, fp32) ----------------
__global__ void colsum_k(const float* __restrict__ hs, float* __restrict__ colsum){
    int i = blockIdx.x*256 + threadIdx.x;   // b*512 + c
    if(i >= BB*512) return;
    int b = i >> 9, c = i & 511;
    const float* p = hs + (size_t)b*NN*512 + c;
    float s = 0.f;
    for(int n=0;n<NN;n++) s += p[(size_t)n*512];
    colsum[i] = s;
}

// ---------------- combine: max over 8 tiles; mean = colsum@w/1024 (fp32); + bias ----------------
__global__ __launch_bounds__(256) void pool_final2_k(const float* __restrict__ pmax,
                                                     const float* __restrict__ colsum,
                                                     const float* __restrict__ w,
                                                     const float* __restrict__ pb,
                                                     float* __restrict__ pooled){
    int i = blockIdx.x*256 + threadIdx.x;   // b*1024 + o
    int b = i >> 10, o = i & 1023;
    __shared__ float cs[512];
    for(int l=threadIdx.x; l<512; l+=256) cs[l] = colsum[b*512 + l];
    __syncthreads();
    float m = -3.402823466e38f;
    #pragma unroll
    for(int t=0;t<8;t++) m = fmaxf(m, pmax[((size_t)b*8 + t)*1024 + o]);
    float s = 0.f;
    const float4* w4 = (const float4*)(w + (size_t)o*512);
    const float4* c4 = (const float4*)cs;
    for(int d=0; d<128; d++){
        float4 wv = w4[d]; float4 cv = c4[d];
        s = fmaf(cv.x, wv.x, s); s = fmaf(cv.y, wv.y, s);
        s = fmaf(cv.z, wv.z, s); s = fmaf(cv.w, wv.w, s);
    }
    float bias = pb[o];
    pooled[b*2048 + o]        = m + bias;
    pooled[b*2048 + 1024 + o] = s * (1.f/1024.f) + bias;
}

// ---------------- head FC + BatchNorm(batch of 16) + leaky; one block per feature ----------------
template<int IN>
__global__ __launch_bounds__(256) void head_bn_k(const float* __restrict__ in, const float* __restrict__ w,
                                                 const float* __restrict__ bias, const float* __restrict__ g,
                                                 const float* __restrict__ bt, float* __restrict__ out, int OUT){
    int o = blockIdx.x;
    int tid = threadIdx.x, bb = tid >> 4, s = tid & 15;
    const float* ir = in + (size_t)bb*IN;
    const float* wr = w  + (size_t)o*IN;
    float acc = 0.f;
    for(int d=s; d<IN; d+=16) acc = fmaf(ir[d], wr[d], acc);
    #pragma unroll
    for(int off=8; off>0; off>>=1) acc += __shfl_xor(acc, off);
    __shared__ float vals[16];
    __shared__ float stats[2];
    if(s == 0) vals[bb] = acc + bias[o];
    __syncthreads();
    if(tid == 0){
        float mu = 0.f;
        for(int q=0;q<16;q++) mu += vals[q];
        mu *= (1.f/16.f);
        float var = 0.f;
        for(int q=0;q<16;q++){ float d = vals[q]-mu; var = fmaf(d,d,var); }
        var *= (1.f/16.f);
        stats[0] = mu; stats[1] = rsqrtf(var + 1e-5f);
    }
    __syncthreads();
    if(s == 0){
        float v = (vals[bb]-stats[0])*stats[1]*g[o] + bt[o];
        v = (v > 0.f) ? v : 0.2f*v;
        out[(size_t)bb*OUT + o] = v;
    }
}

// ---------------- final linear -> f32 out [16,40] ----------------
__global__ __launch_bounds__(256) void head_out_k(const float* __restrict__ in, const float* __restrict__ w,
                                                  const float* __restrict__ bias, float* __restrict__ out){
    int o = blockIdx.x;   // 40
    int tid = threadIdx.x, bb = tid >> 4, s = tid & 15;
    const float* ir = in + (size_t)bb*256;
    float acc = 0.f;
    for(int d=s; d<256; d+=16) acc = fmaf(ir[d], w[o*256+d], acc);
    #pragma unroll
    for(int off=8; off>0; off>>=1) acc += __shfl_xor(acc, off);
    if(s == 0) out[bb*40 + o] = acc + bias[o];
}

extern "C" void kernel_launch(void* const* d_in, const int* in_sizes, int n_in,
                              void* d_out, int out_size, void* d_ws, size_t ws_size,
                              hipStream_t stream) {
    const float* x       = (const float*)d_in[0];
    const float* th[4]   = {(const float*)d_in[1], (const float*)d_in[3], (const float*)d_in[5], (const float*)d_in[7]};
    const float* ph[4]   = {(const float*)d_in[2], (const float*)d_in[4], (const float*)d_in[6], (const float*)d_in[8]};
    const float* proj_w  = (const float*)d_in[9];
    const float* proj_b  = (const float*)d_in[10];
    const float* emb0_w  = (const float*)d_in[11];
    const float* emb0_b  = (const float*)d_in[12];
    const float* bn0_g   = (const float*)d_in[13];
    const float* bn0_b   = (const float*)d_in[14];
    const float* emb1_w  = (const float*)d_in[15];
    const float* emb1_b  = (const float*)d_in[16];
    const float* bn1_g   = (const float*)d_in[17];
    const float* bn1_b   = (const float*)d_in[18];
    const float* out_w   = (const float*)d_in[19];
    const float* out_b   = (const float*)d_in[20];
    float* outp = (float*)d_out;

    // workspace layout (float elements) — REQ unchanged (guard passed at 68.5 MB)
    const size_t OFF_HS  = 0;                       // 16384 x 512 = 8,388,608
    const size_t OFF_T   = 8388608;                 // T outputs (4,194,304)
    const size_t OFF_U   = 12582912;                // hT (<=2,097,152) then hsbf
    const size_t OFF_SQN = 16777216;                // 16384
    const size_t OFF_IDX = 16793600;                // 16384 x 20 ints = 327,680
    const size_t REQ_FL  = 17121280;
    const size_t REQ     = REQ_FL * 4;              // 68,485,120 bytes

    if(ws_size < REQ){
        fallback_k<<<(out_size+255)/256, 256, 0, stream>>>(outp, out_size, (float)((double)ws_size*1e-6));
        return;
    }

    float* Wf   = (float*)d_ws;
    float* hs   = Wf + OFF_HS;
    float* T    = Wf + OFF_T;
    float* hT   = Wf + OFF_U;                       // hT in old U region (no T alias)
    float* sqn  = Wf + OFF_SQN;
    int*   idxb = (int*)(Wf + OFF_IDX);
    // post-layer aliases (T region dead after last gather):
    float* pmax   = T;                                  // 131,072 fl
    float* colsum = T + 131072;
    float* pooled = T + 147456;
    float* z0     = T + 180224;
    float* z1     = T + 188416;
    unsigned short* wbf  = (unsigned short*)(T + 200704);   // 524,288 bf16 (inside T region)
    unsigned short* hsbf = (unsigned short*)(Wf + OFF_U);   // old U region (hT dead after layer 3)

    // ---- layer 0: h=x (S=3,D=3) -> O=64 at hs ch 0     (grid = 2048 knn + 256 feat, interleaved)
    transpose3s_k<<<64,256,0,stream>>>(x, hT, sqn);
    knnfeat_k<3,64><<<2304,256,0,stream>>>(hT, sqn, idxb, x, 3, th[0], ph[0], T, hs + 0);
    gather2_k<64><<<BB*NN/4,256,0,stream>>>(T, idxb, hs + 0);

    // ---- layer 1: h=hs[:,0:64] (S=512,D=64) -> O=64 at ch 64
    transq_k<64><<<dim3(16,16),256,0,stream>>>(hs + 0, hT, sqn);
    knnfeat_k<64,64><<<2304,256,0,stream>>>(hT, sqn, idxb, hs + 0, 512, th[1], ph[1], T, hs + 64);
    gather2_k<64><<<BB*NN/4,256,0,stream>>>(T, idxb, hs + 64);

    // ---- layer 2: h=hs[:,64:128] (D=64) -> O=128 at ch 128   (2048 + 512)
    transq_k<64><<<dim3(16,16),256,0,stream>>>(hs + 64, hT, sqn);
    knnfeat_k<64,128><<<2560,256,0,stream>>>(hT, sqn, idxb, hs + 64, 512, th[2], ph[2], T, hs + 128);
    gather2_k<128><<<BB*NN/2,256,0,stream>>>(T, idxb, hs + 128);

    // ---- layer 3: h=hs[:,128:256] (D=128) -> O=256 at ch 256  (2048 + 1024)
    transq_k<128><<<dim3(16,16),256,0,stream>>>(hs + 128, hT, sqn);
    knnfeat_k<128,256><<<3072,256,0,stream>>>(hT, sqn, idxb, hs + 128, 512, th[3], ph[3], T, hs + 256);
    gather2_k<256><<<BB*NN,256,0,stream>>>(T, idxb, hs + 256);

    // ---- casts (hT dead; hsbf reuses that region; wbf corner of T region)
    castall_k<<<4096+256,256,0,stream>>>(hs, hsbf, proj_w, wbf);

    // ---- projection + pooling (max via bf16 MFMA GEMM; mean via fp32 colsum @ w)
    proj3_k<<<1024,256,0,stream>>>(hsbf, wbf, pmax);
    colsum_k<<<32,256,0,stream>>>(hs, colsum);
    pool_final2_k<<<64,256,0,stream>>>(pmax, colsum, proj_w, proj_b, pooled);

    // ---- head
    head_bn_k<2048><<<512,256,0,stream>>>(pooled, emb0_w, emb0_b, bn0_g, bn0_b, z0, 512);
    head_bn_k<512><<<256,256,0,stream>>>(z0, emb1_w, emb1_b, bn1_g, bn1_b, z1, 256);
    head_out_k<<<40,256,0,stream>>>(z1, out_w, out_b, outp);
}